// Round 1
// baseline (182.786 us; speedup 1.0000x reference)
//
#include <hip/hip_runtime.h>

#define T_TOK 32768   // B*S
#define NQ    8
#define FFN   2048
#define EMB   512
#define BM    128
#define BN    128
#define BK    64
#define NCHUNK (FFN / BK)   // 32
#define HPAD  72            // h_lds row stride in shorts (144 B, 16B-aligned)

typedef __attribute__((ext_vector_type(8))) short  short8;
typedef __attribute__((ext_vector_type(4))) float  float4v;

__device__ __forceinline__ unsigned short f2bf(float f) {
  unsigned int u = __float_as_uint(f);
  u += 0x7fffu + ((u >> 16) & 1u);
  return (unsigned short)(u >> 16);
}

__device__ __forceinline__ unsigned pk2bf(float lo, float hi) {
#if __has_builtin(__builtin_amdgcn_cvt_pk_bf16_f32)
  typedef __attribute__((ext_vector_type(2))) __bf16 bf2;
  bf2 p = __builtin_amdgcn_cvt_pk_bf16_f32(lo, hi);
  return *(unsigned*)&p;
#else
  return (unsigned)f2bf(lo) | ((unsigned)f2bf(hi) << 16);
#endif
}

// ---------------------------------------------------------------------------
// prep_all: tiled transpose W2[FFN][EMB] fp32 -> w2t[EMB][FFN] bf16,
//           plus w1t[f][i] bf16 from W1[i][f] (blockIdx.x==0 column).
// ---------------------------------------------------------------------------
__global__ void prep_all(const float* __restrict__ W1,
                         const float* __restrict__ W2,
                         unsigned short* __restrict__ w1t,
                         unsigned short* __restrict__ w2t) {
  __shared__ float t[32][33];
  const int kb = blockIdx.x * 32;   // FFN tile
  const int nb = blockIdx.y * 32;   // EMB tile
  const int c = threadIdx.x & 31, r0 = threadIdx.x >> 5;
#pragma unroll
  for (int p = 0; p < 4; ++p) {
    int r = r0 + p * 8;
    t[r][c] = W2[(size_t)(kb + r) * EMB + nb + c];
  }
  __syncthreads();
#pragma unroll
  for (int p = 0; p < 4; ++p) {
    int r = r0 + p * 8;
    w2t[(size_t)(nb + r) * FFN + kb + c] = f2bf(t[c][r]);
  }
  if (blockIdx.x == 0) {
    const int base = blockIdx.y * 1024 + threadIdx.x * 4;
#pragma unroll
    for (int e = 0; e < 4; ++e) {
      int idx = base + e;
      int f = idx >> 3, i = idx & 7;
      w1t[idx] = f2bf(W1[i * FFN + f]);
    }
  }
}

// ---------------------------------------------------------------------------
// Fused main, R4: counted-vmcnt pipeline (T3/T4-lite).
//   - w2 chunk double-buffered via global_load_lds, prefetched 1 chunk ahead;
//     loads stay in flight ACROSS the barriers (s_waitcnt vmcnt(4), never 0
//     inside the loop) instead of the __syncthreads vmcnt(0) drain.
//   - w1/b1 staged to LDS (double-buffered) one chunk ahead -> zero
//     compiler-tracked VMEM in the loop, so manual vmcnt math is exact:
//     per-wave queue = [W2(k):4, W1B1(k+1):2, W2(k+1):4] -> vmcnt(4).
//   - raw s_barrier + sched_barrier(0) fences replace __syncthreads.
//   LDS = h 18432 + w2 2x16384 + w1 2x1024 + b1 2x256 = 53760 B -> 3 blk/CU.
// ---------------------------------------------------------------------------
__global__ __launch_bounds__(256, 3) void ffq_main(
    const float* __restrict__ x,
    const float* __restrict__ theta,
    const unsigned short* __restrict__ w1t,
    const float* __restrict__ b1,
    const unsigned short* __restrict__ w2t,
    const float* __restrict__ b2,
    float* __restrict__ out) {

  __shared__ __align__(16) unsigned short h_lds[BM][HPAD];      // 18432 B
  __shared__ __align__(16) unsigned short w2_lds[2][BN * BK];   // 32768 B
  __shared__ __align__(16) unsigned short w1_lds[2][BK * NQ];   //  2048 B
  __shared__ __align__(16) float          b1_lds[2][BK];        //   512 B

  const int tid  = threadIdx.x;
  const int wave = tid >> 6;
  const int lane = tid & 63;
  const int l15  = lane & 15;
  const int quad = lane >> 4;
  const int tok0 = blockIdx.x * BM;
  const int n0   = blockIdx.y * BN;
  const int wr   = wave >> 1;   // GEMM2 wave row (64 tokens)
  const int wc   = wave & 1;    // GEMM2 wave col (64 emb)

  // ---- qc B-frags for GEMM1 (this wave's 32 tokens), computed once ----
  float cth[8];
  {
    const float4* tp = (const float4*)theta;
    float4 t0 = tp[0], t1 = tp[1];
    cth[0] = __cosf(t0.x); cth[1] = __cosf(t0.y);
    cth[2] = __cosf(t0.z); cth[3] = __cosf(t0.w);
    cth[4] = __cosf(t1.x); cth[5] = __cosf(t1.y);
    cth[6] = __cosf(t1.z); cth[7] = __cosf(t1.w);
  }
  short8 bq[2];
#pragma unroll
  for (int g = 0; g < 2; ++g) {
    short8 v = (short8){0,0,0,0,0,0,0,0};
    if (lane < 16) {
      int tok = tok0 + 32 * wave + 16 * g + lane;
      const float4* xp = (const float4*)(x + (size_t)tok * NQ);
      float4 x0 = xp[0], x1 = xp[1];
      float q0 = __cosf(x0.x) * cth[0], q1 = __cosf(x0.y) * cth[1];
      float q2 = __cosf(x0.z) * cth[2], q3 = __cosf(x0.w) * cth[3];
      float q4 = __cosf(x1.x) * cth[4], q5 = __cosf(x1.y) * cth[5];
      float q6 = __cosf(x1.z) * cth[6], q7 = __cosf(x1.w) * cth[7];
      uint4 uu;
      uu.x = pk2bf(q0, q1); uu.y = pk2bf(q2, q3);
      uu.z = pk2bf(q4, q5); uu.w = pk2bf(q6, q7);
      v = *(short8*)&uu;
    }
    bq[g] = v;
  }

  // ---- staging helpers (global_load_lds only; all counted manually) ----
  const int sw_r = tid >> 3;   // w2 row within 32-row group
  const int sw_c = tid & 7;    // w2 stored 16B-chunk index

  auto stage_w1b1 = [&](int kc_, int b_) {
    // w1 chunk: 64 rows x 16B, every wave issues the full (duplicate) copy
    // so per-wave vmcnt counting stays uniform (+2 per wave).
    const int k0_ = kc_ * BK;
    __builtin_amdgcn_global_load_lds(
        (const __attribute__((address_space(1))) void*)(w1t + (size_t)(k0_ + lane) * NQ),
        (__attribute__((address_space(3))) void*)(&w1_lds[b_][lane * NQ]), 16, 0, 0);
    __builtin_amdgcn_global_load_lds(
        (const __attribute__((address_space(1))) void*)(b1 + k0_ + lane),
        (__attribute__((address_space(3))) void*)(&b1_lds[b_][lane]), 4, 0, 0);
  };

  auto stage_w2 = [&](int kc_, int b_) {
    const int k0_ = kc_ * BK;
#pragma unroll
    for (int issue = 0; issue < 4; ++issue) {
      const int row    = issue * 32 + sw_r;     // local n, 0..127
      const int gchunk = sw_c ^ (row & 7);      // 16B XOR swizzle
      __builtin_amdgcn_global_load_lds(
          (const __attribute__((address_space(1))) void*)(
              w2t + (size_t)(n0 + row) * FFN + k0_ + gchunk * 8),
          (__attribute__((address_space(3))) void*)(&w2_lds[b_][issue * 2048 + tid * 8]),
          16, 0, 0);
    }
  };

  float4v acc[4][4];
#pragma unroll
  for (int i = 0; i < 4; ++i)
#pragma unroll
    for (int j = 0; j < 4; ++j)
      acc[i][j] = (float4v){0.f, 0.f, 0.f, 0.f};

  // ---- prologue: stage chunk 0; publish w1/b1(0); keep W2(0) in flight ----
  stage_w1b1(0, 0);
  stage_w2(0, 0);
  asm volatile("s_waitcnt vmcnt(4)" ::: "memory");   // w1b1(0) landed
  __builtin_amdgcn_s_barrier();
  __builtin_amdgcn_sched_barrier(0);

  for (int kc = 0; kc < NCHUNK; ++kc) {
    const int buf  = kc & 1;
    const int nbuf = buf ^ 1;
    const int nc   = (kc + 1 < NCHUNK) ? (kc + 1) : (NCHUNK - 1);  // clamp keeps
                                                                   // vmcnt uniform

    // ---- GEMM1 frags from LDS (published by barrier E of prev iter) ----
    short8 aw[4];
    float4 bias[4];
#pragma unroll
    for (int kt = 0; kt < 4; ++kt) {
      aw[kt]   = *(const short8*)&w1_lds[buf][(kt * 16 + l15) * NQ];
      bias[kt] = *(const float4*)&b1_lds[buf][kt * 16 + quad * 4];
    }

    // prefetch next chunk's w1/b1 into the other buffer (+2 vmcnt)
    stage_w1b1(nc, nbuf);

    // ---- GEMM1 + bias + relu + pack (results kept in regs across barrier) --
    uint2 p0[4], p1[4];
#pragma unroll
    for (int kt = 0; kt < 4; ++kt) {
      float4v c0 = (float4v){0.f, 0.f, 0.f, 0.f};
      float4v c1 = (float4v){0.f, 0.f, 0.f, 0.f};
      c0 = __builtin_amdgcn_mfma_f32_16x16x32_bf16(aw[kt], bq[0], c0, 0, 0, 0);
      c1 = __builtin_amdgcn_mfma_f32_16x16x32_bf16(aw[kt], bq[1], c1, 0, 0, 0);
      float v0[4], v1[4];
#pragma unroll
      for (int r = 0; r < 4; ++r) {
        float a0 = c0[r] + bias[kt][r]; v0[r] = a0 > 0.f ? a0 : 0.f;
        float a1 = c1[r] + bias[kt][r]; v1[r] = a1 > 0.f ? a1 : 0.f;
      }
      p0[kt].x = pk2bf(v0[0], v0[1]); p0[kt].y = pk2bf(v0[2], v0[3]);
      p1[kt].x = pk2bf(v1[0], v1[1]); p1[kt].y = pk2bf(v1[2], v1[3]);
    }

    __builtin_amdgcn_s_barrier();          // M: GEMM2(kc-1) readers all done
    __builtin_amdgcn_sched_barrier(0);

    // prefetch next w2 chunk into freed buffer (+4 vmcnt, in flight across E)
    stage_w2(nc, nbuf);

    // publish h(kc)
#pragma unroll
    for (int kt = 0; kt < 4; ++kt) {
      *((uint2*)&h_lds[32 * wave + l15][kt * 16 + quad * 4])      = p0[kt];
      *((uint2*)&h_lds[32 * wave + 16 + l15][kt * 16 + quad * 4]) = p1[kt];
    }

    // retire W2(kc) + W1B1(kc+1); leave W2(kc+1) (4 newest) in flight
    asm volatile("s_waitcnt vmcnt(4) lgkmcnt(0)" ::: "memory");
    __builtin_amdgcn_s_barrier();          // E: h(kc) + w2[buf] ready
    __builtin_amdgcn_sched_barrier(0);

    // ---- GEMM2: acc += h_tile @ w2_chunk (both from LDS) ----
#pragma unroll
    for (int ks = 0; ks < 2; ++ks) {
      short8 af[4], bf[4];
#pragma unroll
      for (int mt = 0; mt < 4; ++mt)
        af[mt] = *(const short8*)&h_lds[wr * 64 + mt * 16 + l15]
                                       [ks * 32 + quad * 8];
#pragma unroll
      for (int nt = 0; nt < 4; ++nt) {
        const int n  = wc * 64 + nt * 16 + l15;
        const int sc = (ks * 4 + quad) ^ (n & 7);   // undo XOR swizzle
        bf[nt] = *(const short8*)&w2_lds[buf][n * BK + sc * 8];
      }
#pragma unroll
      for (int mt = 0; mt < 4; ++mt)
#pragma unroll
        for (int nt = 0; nt < 4; ++nt)
          acc[mt][nt] = __builtin_amdgcn_mfma_f32_16x16x32_bf16(
              af[mt], bf[nt], acc[mt][nt], 0, 0, 0);
    }
  }

  // drain the (harmless, clamped) last-iteration prefetch before LDS dies
  asm volatile("s_waitcnt vmcnt(0)" ::: "memory");

  // ---- epilogue: + b2, fp32 store ----
#pragma unroll
  for (int nt = 0; nt < 4; ++nt) {
    const int col = n0 + wc * 64 + nt * 16 + l15;
    const float bv = b2[col];
#pragma unroll
    for (int mt = 0; mt < 4; ++mt) {
      const int row0 = tok0 + wr * 64 + mt * 16 + quad * 4;
#pragma unroll
      for (int r = 0; r < 4; ++r) {
        out[(size_t)(row0 + r) * EMB + col] = acc[mt][nt][r] + bv;
      }
    }
  }
}

extern "C" void kernel_launch(void* const* d_in, const int* in_sizes, int n_in,
                              void* d_out, int out_size, void* d_ws, size_t ws_size,
                              hipStream_t stream) {
  const float* x     = (const float*)d_in[0];
  const float* theta = (const float*)d_in[1];
  const float* W1    = (const float*)d_in[2];
  const float* b1    = (const float*)d_in[3];
  const float* W2    = (const float*)d_in[4];
  const float* b2    = (const float*)d_in[5];
  float* out = (float*)d_out;

  unsigned short* w1t = (unsigned short*)d_ws;       // 16384 bf16
  unsigned short* w2t = w1t + FFN * NQ;              // 1048576 bf16

  prep_all<<<dim3(FFN / 32, EMB / 32), 256, 0, stream>>>(W1, W2, w1t, w2t);

  dim3 grid(T_TOK / BM, EMB / BN);  // (256, 4) = 1024 blocks
  ffq_main<<<grid, 256, 0, stream>>>(x, theta, w1t, b1, w2t, b2, out);
}

// Round 2
// 171.608 us; speedup vs baseline: 1.0651x; 1.0651x over previous
//
#include <hip/hip_runtime.h>

#define T_TOK 32768   // B*S
#define NQ    8
#define FFN   2048
#define EMB   512
#define BM    128
#define BN    128
#define BK    32
#define NCHUNK (FFN / BK)   // 64
#define HROW  36            // wave-private h row stride in shorts (72 B)

typedef __attribute__((ext_vector_type(8))) short  short8;
typedef __attribute__((ext_vector_type(4))) float  float4v;

__device__ __forceinline__ unsigned short f2bf(float f) {
  unsigned int u = __float_as_uint(f);
  u += 0x7fffu + ((u >> 16) & 1u);
  return (unsigned short)(u >> 16);
}

__device__ __forceinline__ unsigned pk2bf(float lo, float hi) {
#if __has_builtin(__builtin_amdgcn_cvt_pk_bf16_f32)
  typedef __attribute__((ext_vector_type(2))) __bf16 bf2;
  bf2 p = __builtin_amdgcn_cvt_pk_bf16_f32(lo, hi);
  return *(unsigned*)&p;
#else
  return (unsigned)f2bf(lo) | ((unsigned)f2bf(hi) << 16);
#endif
}

// 8B-aligned short8 load (h rows are 72B-strided -> only 8B aligned)
__device__ __forceinline__ short8 ld_h8(const unsigned short* p) {
  uint2 a = *(const uint2*)p;
  uint2 b = *(const uint2*)(p + 4);
  uint4 u; u.x = a.x; u.y = a.y; u.z = b.x; u.w = b.y;
  return *(short8*)&u;
}

// ---------------------------------------------------------------------------
// prep_all: tiled transpose W2[FFN][EMB] fp32 -> w2t[EMB][FFN] bf16,
//           plus w1t[f][i] bf16 from W1[i][f] (blockIdx.x==0 column).
// ---------------------------------------------------------------------------
__global__ void prep_all(const float* __restrict__ W1,
                         const float* __restrict__ W2,
                         unsigned short* __restrict__ w1t,
                         unsigned short* __restrict__ w2t) {
  __shared__ float t[32][33];
  const int kb = blockIdx.x * 32;   // FFN tile
  const int nb = blockIdx.y * 32;   // EMB tile
  const int c = threadIdx.x & 31, r0 = threadIdx.x >> 5;
#pragma unroll
  for (int p = 0; p < 4; ++p) {
    int r = r0 + p * 8;
    t[r][c] = W2[(size_t)(kb + r) * EMB + nb + c];
  }
  __syncthreads();
#pragma unroll
  for (int p = 0; p < 4; ++p) {
    int r = r0 + p * 8;
    w2t[(size_t)(nb + r) * FFN + kb + c] = f2bf(t[c][r]);
  }
  if (blockIdx.x == 0) {
    const int base = blockIdx.y * 1024 + threadIdx.x * 4;
#pragma unroll
    for (int e = 0; e < 4; ++e) {
      int idx = base + e;
      int f = idx >> 3, i = idx & 7;
      w1t[idx] = f2bf(W1[i * FFN + f]);
    }
  }
}

// ---------------------------------------------------------------------------
// Fused main, R5: wave-aligned token ownership -> ONE barrier per chunk.
//   - Each wave owns 32 tokens for BOTH GEMM1 and GEMM2 (acc = 2x8 tiles):
//     h exchange is wave-private LDS (lgkmcnt(0) only, no barrier M).
//   - BK=32, w2 double-buffered (2x8KB) via global_load_lds, prefetched one
//     chunk ahead; the per-chunk vmcnt(0) drain is covered by a FULL chunk
//     of compute. Barrier placed after the drain = everyone's stage landed
//     AND everyone done reading the buffer being overwritten next.
//   - LDS = 16384 (w2) + 9216 (h, 4 x [32][36] swizzle-free padded) = 25600 B
//     -> all 1024 blocks resident (4/CU), unlike R4's 3/CU.
//   - T5 setprio around GEMM2 MFMA cluster (waves now desync within chunk).
// ---------------------------------------------------------------------------
__global__ __launch_bounds__(256, 4) void ffq_main(
    const float* __restrict__ x,
    const float* __restrict__ theta,
    const unsigned short* __restrict__ w1t,
    const float* __restrict__ b1,
    const unsigned short* __restrict__ w2t,
    const float* __restrict__ b2,
    float* __restrict__ out) {

  __shared__ __align__(16) unsigned short w2_lds[2][BN * BK];   // 16384 B
  __shared__ __align__(16) unsigned short h_lds[4][32 * HROW];  //  9216 B

  const int tid  = threadIdx.x;
  const int wave = tid >> 6;
  const int lane = tid & 63;
  const int l15  = lane & 15;
  const int quad = lane >> 4;
  const int tok0 = blockIdx.x * BM;
  const int n0   = blockIdx.y * BN;

  unsigned short* hb = &h_lds[wave][0];

  // ---- qc B-frags for GEMM1 (this wave's 32 tokens), computed once ----
  float cth[8];
  {
    const float4* tp = (const float4*)theta;
    float4 t0 = tp[0], t1 = tp[1];
    cth[0] = __cosf(t0.x); cth[1] = __cosf(t0.y);
    cth[2] = __cosf(t0.z); cth[3] = __cosf(t0.w);
    cth[4] = __cosf(t1.x); cth[5] = __cosf(t1.y);
    cth[6] = __cosf(t1.z); cth[7] = __cosf(t1.w);
  }
  short8 bq[2];
#pragma unroll
  for (int g = 0; g < 2; ++g) {
    short8 v = (short8){0,0,0,0,0,0,0,0};
    if (lane < 16) {
      int tok = tok0 + 32 * wave + 16 * g + lane;
      const float4* xp = (const float4*)(x + (size_t)tok * NQ);
      float4 x0 = xp[0], x1 = xp[1];
      float q0 = __cosf(x0.x) * cth[0], q1 = __cosf(x0.y) * cth[1];
      float q2 = __cosf(x0.z) * cth[2], q3 = __cosf(x0.w) * cth[3];
      float q4 = __cosf(x1.x) * cth[4], q5 = __cosf(x1.y) * cth[5];
      float q6 = __cosf(x1.z) * cth[6], q7 = __cosf(x1.w) * cth[7];
      uint4 uu;
      uu.x = pk2bf(q0, q1); uu.y = pk2bf(q2, q3);
      uu.z = pk2bf(q4, q5); uu.w = pk2bf(q6, q7);
      v = *(short8*)&uu;
    }
    bq[g] = v;
  }

  // ---- w2 staging: linear LDS dest, pre-swizzled global source (m173) ----
  // stored 16B-chunk c of row r holds global chunk gc = c ^ ((r>>1)&3);
  // per-thread: r = issue*64 + (tid>>2), c = tid&3 -> gc constant per thread.
  const int st_row = tid >> 2;
  const int st_gc  = (tid & 3) ^ ((tid >> 3) & 3);

  auto stage_w2 = [&](int kc_, int b_) {
    const int k0_ = kc_ * BK;
#pragma unroll
    for (int issue = 0; issue < 2; ++issue) {
      const int r = issue * 64 + st_row;
      __builtin_amdgcn_global_load_lds(
          (const __attribute__((address_space(1))) void*)(
              w2t + (size_t)(n0 + r) * FFN + k0_ + st_gc * 8),
          (__attribute__((address_space(3))) void*)(
              &w2_lds[b_][issue * 2048 + tid * 8]),
          16, 0, 0);
    }
  };

  float4v acc[2][8];
#pragma unroll
  for (int i = 0; i < 2; ++i)
#pragma unroll
    for (int j = 0; j < 8; ++j)
      acc[i][j] = (float4v){0.f, 0.f, 0.f, 0.f};

  // loop-invariant pieces
  const int bf_c    = quad ^ ((l15 >> 1) & 3);          // w2 read de-swizzle
  const unsigned short* w2r[2] = {
      &w2_lds[0][l15 * BK + bf_c * 8],
      &w2_lds[1][l15 * BK + bf_c * 8]};
  unsigned short* hw0 = hb + l15 * HROW + quad * 4;        // g=0 write base
  unsigned short* hw1 = hb + (16 + l15) * HROW + quad * 4; // g=1 write base
  const unsigned short* hr0 = hb + l15 * HROW + quad * 8;        // mt=0 read
  const unsigned short* hr1 = hb + (16 + l15) * HROW + quad * 8; // mt=1 read

  stage_w2(0, 0);

#pragma unroll 2
  for (int kc = 0; kc < NCHUNK; ++kc) {
    const int buf = kc & 1;
    const int k0  = kc * BK;
    const int nc  = (kc + 1 < NCHUNK) ? kc + 1 : NCHUNK - 1;  // clamp: uniform
                                                              // control flow
    // stage(kc) had a full chunk of compute to land -> cheap drain
    asm volatile("s_waitcnt vmcnt(0)" ::: "memory");
    __builtin_amdgcn_s_barrier();   // all stage(kc) landed; nbuf readers done
    __builtin_amdgcn_sched_barrier(0);

    // ---- w1/b1 frags from global (L1-resident; quads broadcast aw) ----
    // issued BEFORE the stage so the compiler's use-wait is vmcnt(2),
    // leaving stage(kc+1) in flight.
    short8 aw0 = *(const short8*)(w1t + (size_t)(k0 + l15) * NQ);
    short8 aw1 = *(const short8*)(w1t + (size_t)(k0 + 16 + l15) * NQ);
    float4 bi0 = *(const float4*)(b1 + k0 + quad * 4);
    float4 bi1 = *(const float4*)(b1 + k0 + 16 + quad * 4);
    __builtin_amdgcn_sched_barrier(0);

    stage_w2(nc, buf ^ 1);          // prefetch next chunk (stays in flight)
    __builtin_amdgcn_sched_barrier(0);

    // ---- GEMM1: h[tok][f] for this wave's 32 tokens, f in [k0,k0+32) ----
    {
      float4v c00 = (float4v){0.f,0.f,0.f,0.f}, c01 = c00, c10 = c00, c11 = c00;
      c00 = __builtin_amdgcn_mfma_f32_16x16x32_bf16(aw0, bq[0], c00, 0, 0, 0);
      c01 = __builtin_amdgcn_mfma_f32_16x16x32_bf16(aw0, bq[1], c01, 0, 0, 0);
      c10 = __builtin_amdgcn_mfma_f32_16x16x32_bf16(aw1, bq[0], c10, 0, 0, 0);
      c11 = __builtin_amdgcn_mfma_f32_16x16x32_bf16(aw1, bq[1], c11, 0, 0, 0);
      float v00[4], v01[4], v10[4], v11[4];
#pragma unroll
      for (int r = 0; r < 4; ++r) {
        float a;
        a = c00[r] + bi0[r]; v00[r] = a > 0.f ? a : 0.f;
        a = c01[r] + bi0[r]; v01[r] = a > 0.f ? a : 0.f;
        a = c10[r] + bi1[r]; v10[r] = a > 0.f ? a : 0.f;
        a = c11[r] + bi1[r]; v11[r] = a > 0.f ? a : 0.f;
      }
      uint2 p;
      p.x = pk2bf(v00[0], v00[1]); p.y = pk2bf(v00[2], v00[3]);
      *(uint2*)(hw0)      = p;                          // kt=0, g=0
      p.x = pk2bf(v01[0], v01[1]); p.y = pk2bf(v01[2], v01[3]);
      *(uint2*)(hw1)      = p;                          // kt=0, g=1
      p.x = pk2bf(v10[0], v10[1]); p.y = pk2bf(v10[2], v10[3]);
      *(uint2*)(hw0 + 16) = p;                          // kt=1, g=0
      p.x = pk2bf(v11[0], v11[1]); p.y = pk2bf(v11[2], v11[3]);
      *(uint2*)(hw1 + 16) = p;                          // kt=1, g=1
    }

    // wave-private h: same-wave write->read, no barrier needed
    asm volatile("s_waitcnt lgkmcnt(0)" ::: "memory");
    __builtin_amdgcn_sched_barrier(0);

    // ---- GEMM2: acc += h(32xBK) @ w2(BKx128), all frags wave-local ----
    __builtin_amdgcn_s_setprio(1);
    {
      short8 af0 = ld_h8(hr0);
      short8 af1 = ld_h8(hr1);
      const unsigned short* wb = w2r[buf];
#pragma unroll
      for (int nt = 0; nt < 8; ++nt) {
        short8 bf = *(const short8*)(wb + nt * 512);   // nt*16 rows * 32
        acc[0][nt] = __builtin_amdgcn_mfma_f32_16x16x32_bf16(
            af0, bf, acc[0][nt], 0, 0, 0);
        acc[1][nt] = __builtin_amdgcn_mfma_f32_16x16x32_bf16(
            af1, bf, acc[1][nt], 0, 0, 0);
      }
    }
    __builtin_amdgcn_s_setprio(0);
  }

  // drain the clamped last prefetch before LDS goes away
  asm volatile("s_waitcnt vmcnt(0)" ::: "memory");

  // ---- epilogue: + b2, fp32 store ----
#pragma unroll
  for (int nt = 0; nt < 8; ++nt) {
    const int col = n0 + nt * 16 + l15;
    const float bv = b2[col];
#pragma unroll
    for (int mt = 0; mt < 2; ++mt) {
      const int row0 = tok0 + wave * 32 + mt * 16 + quad * 4;
#pragma unroll
      for (int r = 0; r < 4; ++r) {
        out[(size_t)(row0 + r) * EMB + col] = acc[mt][nt][r] + bv;
      }
    }
  }
}

extern "C" void kernel_launch(void* const* d_in, const int* in_sizes, int n_in,
                              void* d_out, int out_size, void* d_ws, size_t ws_size,
                              hipStream_t stream) {
  const float* x     = (const float*)d_in[0];
  const float* theta = (const float*)d_in[1];
  const float* W1    = (const float*)d_in[2];
  const float* b1    = (const float*)d_in[3];
  const float* W2    = (const float*)d_in[4];
  const float* b2    = (const float*)d_in[5];
  float* out = (float*)d_out;

  unsigned short* w1t = (unsigned short*)d_ws;       // 16384 bf16
  unsigned short* w2t = w1t + FFN * NQ;              // 1048576 bf16

  prep_all<<<dim3(FFN / 32, EMB / 32), 256, 0, stream>>>(W1, W2, w1t, w2t);

  dim3 grid(T_TOK / BM, EMB / BN);  // (256, 4) = 1024 blocks = 4/CU resident
  ffq_main<<<grid, 256, 0, stream>>>(x, theta, w1t, b1, w2t, b2, out);
}